// Round 1
// baseline (1337.969 us; speedup 1.0000x reference)
//
#include <hip/hip_runtime.h>
#include <hip/hip_bf16.h>

#define SEQ 4096
#define NB 2
#define DM 512
#define NH 8
#define DK 64

// ---------------------------------------------------------------------------
// Generic fp32 tiled GEMM: C[M,N] = A[M,K] @ B[K,N], row-major, 64x64 tile,
// BK=16, 256 threads, 4x4 micro-tile per thread.
// ---------------------------------------------------------------------------
__global__ __launch_bounds__(256)
void gemm_f32_64x64(const float* __restrict__ A, const float* __restrict__ B,
                    float* __restrict__ C, int M, int N, int K) {
    __shared__ float As[16][68];   // [k][m]  (A^T tile), +4 pad: aligned & low-conflict
    __shared__ float Bs[16][68];   // [k][n]

    const int tid = threadIdx.x;
    const int tx = tid & 15;        // n-quad
    const int ty = tid >> 4;        // m-quad
    const int rowBase = blockIdx.y * 64;
    const int colBase = blockIdx.x * 64;

    const int la_r = tid >> 2;          // 0..63 : m row
    const int la_k = (tid & 3) << 2;    // 0,4,8,12 : k chunk
    const int lb_k = tid >> 4;          // 0..15 : k row
    const int lb_c = (tid & 15) << 2;   // 0..60 : n chunk

    float acc[4][4] = {};

    for (int k0 = 0; k0 < K; k0 += 16) {
        __syncthreads();
        // stage A tile transposed
        float4 av = *(const float4*)&A[(size_t)(rowBase + la_r) * K + k0 + la_k];
        As[la_k + 0][la_r] = av.x;
        As[la_k + 1][la_r] = av.y;
        As[la_k + 2][la_r] = av.z;
        As[la_k + 3][la_r] = av.w;
        // stage B tile
        *(float4*)&Bs[lb_k][lb_c] =
            *(const float4*)&B[(size_t)(k0 + lb_k) * N + colBase + lb_c];
        __syncthreads();

        #pragma unroll
        for (int kk = 0; kk < 16; ++kk) {
            float4 a4 = *(const float4*)&As[kk][ty << 2];
            float4 b4 = *(const float4*)&Bs[kk][tx << 2];
            float ar[4] = {a4.x, a4.y, a4.z, a4.w};
            float br[4] = {b4.x, b4.y, b4.z, b4.w};
            #pragma unroll
            for (int i = 0; i < 4; ++i)
                #pragma unroll
                for (int j = 0; j < 4; ++j)
                    acc[i][j] = fmaf(ar[i], br[j], acc[i][j]);
        }
    }

    #pragma unroll
    for (int i = 0; i < 4; ++i) {
        float4 v = {acc[i][0], acc[i][1], acc[i][2], acc[i][3]};
        *(float4*)&C[(size_t)(rowBase + (ty << 2) + i) * N + colBase + (tx << 2)] = v;
    }
}

// ---------------------------------------------------------------------------
// Flash attention, fp32. One block per (batch, head, 64-row q-tile).
// qkv layout: (B, S, 3, NH, DK) = element ((b*SEQ+s)*3 + m)*DM + h*DK + d
// att layout: (B, S, DM) with column h*DK + d.
// 256 threads; score & PV phases are 64x64 GEMMs with 4x4 micro-tiles.
// Online softmax state (m, l) lives in registers, replicated across the 16
// lanes that share a q-row; row reduce via __shfl_xor over 16 lanes.
// ---------------------------------------------------------------------------
__global__ __launch_bounds__(256)
void flash_attn_f32(const float* __restrict__ qkv, float* __restrict__ att) {
    const int qt = blockIdx.x;   // q tile 0..63
    const int h  = blockIdx.y;
    const int b  = blockIdx.z;

    __shared__ float Qt[64][68];  // [d][q]  pre-scaled by 1/8
    __shared__ float Kt[64][68];  // [d][k]
    __shared__ float Vs[64][68];  // [k][d]
    __shared__ float Pt[64][68];  // [k][q]

    const int tid = threadIdx.x;
    const int tx = tid & 15;
    const int ty = tid >> 4;

    const int lr = tid >> 2;          // 0..63 : tile row
    const int lc = (tid & 3) << 4;    // 0,16,32,48 : d chunk base

    // ---- load Q tile (transposed, scaled) ----
    {
        const size_t base = ((size_t)(b * SEQ + qt * 64 + lr) * 3 + 0) * DM + h * DK;
        #pragma unroll
        for (int u = 0; u < 4; ++u) {
            float4 v = *(const float4*)&qkv[base + lc + u * 4];
            Qt[lc + u * 4 + 0][lr] = v.x * 0.125f;
            Qt[lc + u * 4 + 1][lr] = v.y * 0.125f;
            Qt[lc + u * 4 + 2][lr] = v.z * 0.125f;
            Qt[lc + u * 4 + 3][lr] = v.w * 0.125f;
        }
    }

    float m_run[4] = {-1e30f, -1e30f, -1e30f, -1e30f};
    float l_run[4] = {0.f, 0.f, 0.f, 0.f};
    float o[4][4] = {};

    for (int kt = 0; kt < SEQ / 64; ++kt) {
        __syncthreads();   // prev PV done with Vs/Pt; (1st iter: Q store drains too)
        // ---- stage K (transposed) and V ----
        {
            const size_t kbase = ((size_t)(b * SEQ + kt * 64 + lr) * 3 + 1) * DM + h * DK;
            #pragma unroll
            for (int u = 0; u < 4; ++u) {
                float4 v = *(const float4*)&qkv[kbase + lc + u * 4];
                Kt[lc + u * 4 + 0][lr] = v.x;
                Kt[lc + u * 4 + 1][lr] = v.y;
                Kt[lc + u * 4 + 2][lr] = v.z;
                Kt[lc + u * 4 + 3][lr] = v.w;
            }
            const size_t vbase = ((size_t)(b * SEQ + kt * 64 + lr) * 3 + 2) * DM + h * DK;
            #pragma unroll
            for (int u = 0; u < 4; ++u)
                *(float4*)&Vs[lr][lc + u * 4] = *(const float4*)&qkv[vbase + lc + u * 4];
        }
        __syncthreads();

        // ---- scores: S = (Q/8) @ K^T, 4x4 per thread ----
        float s[4][4] = {};
        #pragma unroll 8
        for (int d = 0; d < 64; ++d) {
            float4 q4 = *(const float4*)&Qt[d][ty << 2];
            float4 k4 = *(const float4*)&Kt[d][tx << 2];
            float qr[4] = {q4.x, q4.y, q4.z, q4.w};
            float kr[4] = {k4.x, k4.y, k4.z, k4.w};
            #pragma unroll
            for (int i = 0; i < 4; ++i)
                #pragma unroll
                for (int j = 0; j < 4; ++j)
                    s[i][j] = fmaf(qr[i], kr[j], s[i][j]);
        }

        // ---- online softmax (row = q), write P^T to LDS ----
        #pragma unroll
        for (int i = 0; i < 4; ++i) {
            float mx = fmaxf(fmaxf(s[i][0], s[i][1]), fmaxf(s[i][2], s[i][3]));
            #pragma unroll
            for (int off = 1; off < 16; off <<= 1)
                mx = fmaxf(mx, __shfl_xor(mx, off));
            const float mnew  = fmaxf(m_run[i], mx);
            const float alpha = __expf(m_run[i] - mnew);
            float p0 = __expf(s[i][0] - mnew);
            float p1 = __expf(s[i][1] - mnew);
            float p2 = __expf(s[i][2] - mnew);
            float p3 = __expf(s[i][3] - mnew);
            float rs = (p0 + p1) + (p2 + p3);
            #pragma unroll
            for (int off = 1; off < 16; off <<= 1)
                rs += __shfl_xor(rs, off);
            l_run[i] = l_run[i] * alpha + rs;
            m_run[i] = mnew;
            o[i][0] *= alpha; o[i][1] *= alpha; o[i][2] *= alpha; o[i][3] *= alpha;
            Pt[(tx << 2) + 0][(ty << 2) + i] = p0;
            Pt[(tx << 2) + 1][(ty << 2) + i] = p1;
            Pt[(tx << 2) + 2][(ty << 2) + i] = p2;
            Pt[(tx << 2) + 3][(ty << 2) + i] = p3;
        }
        __syncthreads();

        // ---- O += P @ V ----
        #pragma unroll 8
        for (int k = 0; k < 64; ++k) {
            float4 p4 = *(const float4*)&Pt[k][ty << 2];
            float4 v4 = *(const float4*)&Vs[k][tx << 2];
            float pr[4] = {p4.x, p4.y, p4.z, p4.w};
            float vr[4] = {v4.x, v4.y, v4.z, v4.w};
            #pragma unroll
            for (int i = 0; i < 4; ++i)
                #pragma unroll
                for (int j = 0; j < 4; ++j)
                    o[i][j] = fmaf(pr[i], vr[j], o[i][j]);
        }
    }

    // ---- epilogue: normalize and store ----
    #pragma unroll
    for (int i = 0; i < 4; ++i) {
        const float inv = 1.0f / l_run[i];
        float4 v = {o[i][0] * inv, o[i][1] * inv, o[i][2] * inv, o[i][3] * inv};
        const size_t s_idx = (size_t)(b * SEQ + qt * 64 + (ty << 2) + i);
        *(float4*)&att[s_idx * DM + h * DK + (tx << 2)] = v;
    }
}

// ---------------------------------------------------------------------------
extern "C" void kernel_launch(void* const* d_in, const int* in_sizes, int n_in,
                              void* d_out, int out_size, void* d_ws, size_t ws_size,
                              hipStream_t stream) {
    const float* x    = (const float*)d_in[0];   // (2,4096,512)
    const float* Wqkv = (const float*)d_in[1];   // (512,1536)
    const float* Wout = (const float*)d_in[2];   // (512,512)
    float* out = (float*)d_out;                  // (2,4096,512)

    float* qkv = (float*)d_ws;                          // 8192*1536 fp32 = 48 MB
    float* attn = qkv + (size_t)NB * SEQ * 3 * DM;      // 8192*512 fp32 = 16 MB

    const int M = NB * SEQ;   // 8192

    // 1) qkv = x @ W_qkv
    gemm_f32_64x64<<<dim3((3 * DM) / 64, M / 64), 256, 0, stream>>>(
        x, Wqkv, qkv, M, 3 * DM, DM);

    // 2) flash attention per (b, h, q-tile)
    flash_attn_f32<<<dim3(SEQ / 64, NH, NB), 256, 0, stream>>>(qkv, attn);

    // 3) out = attn @ W_out
    gemm_f32_64x64<<<dim3(DM / 64, M / 64), 256, 0, stream>>>(
        attn, Wout, out, M, DM, DM);
}

// Round 3
// 366.518 us; speedup vs baseline: 3.6505x; 3.6505x over previous
//
#include <hip/hip_runtime.h>
#include <hip/hip_bf16.h>

#define SEQ 4096
#define NB 2
#define DM 512
#define NH 8
#define DK 64

typedef __bf16 bf16;
typedef __bf16 bf16x4 __attribute__((ext_vector_type(4)));
typedef __bf16 bf16x8 __attribute__((ext_vector_type(8)));
typedef float  f32x4 __attribute__((ext_vector_type(4)));

__device__ __forceinline__ f32x4 mfma16(bf16x8 a, bf16x8 b, f32x4 c) {
    return __builtin_amdgcn_mfma_f32_16x16x32_bf16(a, b, c, 0, 0, 0);
}

// LDS rows are 64 bf16 (128 B). XOR-swizzle 16B slot by row (G4 fix).
// e = element offset within row (multiple of 4).
__device__ __forceinline__ int swzE(int row, int e) {
    return row * 64 + (e ^ ((row & 7) << 3));
}

__device__ __forceinline__ void split2(float f, bf16& h, bf16& l) {
    bf16 hh = (bf16)f;
    h = hh;
    l = (bf16)(f - (float)hh);
}

// Load 8 contiguous fp32, scale, split into hi/lo bf16x8.
__device__ __forceinline__ void split8(const float* __restrict__ p, float scale,
                                       bf16x8& h, bf16x8& l) {
    const float4 v0 = *(const float4*)p;
    const float4 v1 = *(const float4*)(p + 4);
    float f0 = v0.x * scale, f1 = v0.y * scale, f2 = v0.z * scale, f3 = v0.w * scale;
    float f4 = v1.x * scale, f5 = v1.y * scale, f6 = v1.z * scale, f7 = v1.w * scale;
    bf16 h0 = (bf16)f0, h1 = (bf16)f1, h2 = (bf16)f2, h3 = (bf16)f3;
    bf16 h4 = (bf16)f4, h5 = (bf16)f5, h6 = (bf16)f6, h7 = (bf16)f7;
    h = (bf16x8){h0, h1, h2, h3, h4, h5, h6, h7};
    l = (bf16x8){(bf16)(f0 - (float)h0), (bf16)(f1 - (float)h1),
                 (bf16)(f2 - (float)h2), (bf16)(f3 - (float)h3),
                 (bf16)(f4 - (float)h4), (bf16)(f5 - (float)h5),
                 (bf16)(f6 - (float)h6), (bf16)(f7 - (float)h7)};
}

// ---------------------------------------------------------------------------
// Transpose + split weights: W[K][N] fp32 -> Wt_hi/lo[N][K] bf16.
// ---------------------------------------------------------------------------
__global__ __launch_bounds__(256)
void prep_w(const float* __restrict__ W, bf16* __restrict__ Wth,
            bf16* __restrict__ Wtl, int K, int N) {
    __shared__ float T[64][65];
    const int k0 = blockIdx.x * 64, n0 = blockIdx.y * 64;
    const int t = threadIdx.x;
    #pragma unroll
    for (int i = 0; i < 4; ++i) {
        int r = i * 16 + (t >> 4);
        int c = (t & 15) * 4;
        float4 v = *(const float4*)&W[(size_t)(k0 + r) * N + n0 + c];
        T[r][c + 0] = v.x; T[r][c + 1] = v.y; T[r][c + 2] = v.z; T[r][c + 3] = v.w;
    }
    __syncthreads();
    #pragma unroll
    for (int i = 0; i < 4; ++i) {
        int n = i * 16 + (t >> 4);
        int c = (t & 15) * 4;
        float a0 = T[c + 0][n], a1 = T[c + 1][n], a2 = T[c + 2][n], a3 = T[c + 3][n];
        bf16 h0 = (bf16)a0, h1 = (bf16)a1, h2 = (bf16)a2, h3 = (bf16)a3;
        bf16x4 hv = (bf16x4){h0, h1, h2, h3};
        bf16x4 lv = (bf16x4){(bf16)(a0 - (float)h0), (bf16)(a1 - (float)h1),
                             (bf16)(a2 - (float)h2), (bf16)(a3 - (float)h3)};
        *(bf16x4*)&Wth[(size_t)(n0 + n) * K + k0 + c] = hv;
        *(bf16x4*)&Wtl[(size_t)(n0 + n) * K + k0 + c] = lv;
    }
}

// ---------------------------------------------------------------------------
// Split-bf16 MFMA GEMM: C[M,N] fp32 = A[M,K] fp32 @ Bt[N,K]^T (pre-split bf16).
// 128x128 tile, BK=64, 4 waves of 64x64 (4x4 16x16x32 frags), 3-term split.
// ---------------------------------------------------------------------------
__global__ __launch_bounds__(256, 2)
void gemm_split(const float* __restrict__ A, const bf16* __restrict__ Bth,
                const bf16* __restrict__ Btl, float* __restrict__ C,
                int M, int N, int K) {
    __shared__ bf16 Ah[128 * 64], Al[128 * 64], Bh[128 * 64], Bl[128 * 64];
    const int t = threadIdx.x;
    const int lane = t & 63, w = t >> 6;
    const int l15 = lane & 15, g = lane >> 4;
    const int wm = (w >> 1) * 64, wn = (w & 1) * 64;
    const int rowA = blockIdx.y * 128;
    const int colB = blockIdx.x * 128;
    const int sr = t >> 1;          // staging row 0..127
    const int sc = (t & 1) * 32;    // staging k-chunk

    f32x4 acc[4][4] = {};

    for (int k0 = 0; k0 < K; k0 += 64) {
        __syncthreads();
        #pragma unroll
        for (int u = 0; u < 4; ++u) {   // A: fp32 -> hi/lo
            bf16x8 h, l;
            split8(&A[(size_t)(rowA + sr) * K + k0 + sc + u * 8], 1.0f, h, l);
            int off = swzE(sr, sc + u * 8);
            *(bf16x8*)&Ah[off] = h;
            *(bf16x8*)&Al[off] = l;
        }
        #pragma unroll
        for (int u = 0; u < 4; ++u) {   // B: pre-split copy
            int off = swzE(sr, sc + u * 8);
            *(bf16x8*)&Bh[off] = *(const bf16x8*)&Bth[(size_t)(colB + sr) * K + k0 + sc + u * 8];
            *(bf16x8*)&Bl[off] = *(const bf16x8*)&Btl[(size_t)(colB + sr) * K + k0 + sc + u * 8];
        }
        __syncthreads();
        #pragma unroll
        for (int kst = 0; kst < 2; ++kst) {
            bf16x8 ah[4], al[4];
            #pragma unroll
            for (int mi = 0; mi < 4; ++mi) {
                int off = swzE(wm + mi * 16 + l15, kst * 32 + g * 8);
                ah[mi] = *(const bf16x8*)&Ah[off];
                al[mi] = *(const bf16x8*)&Al[off];
            }
            #pragma unroll
            for (int ni = 0; ni < 4; ++ni) {
                int off = swzE(wn + ni * 16 + l15, kst * 32 + g * 8);
                bf16x8 bh = *(const bf16x8*)&Bh[off];
                bf16x8 bl = *(const bf16x8*)&Bl[off];
                #pragma unroll
                for (int mi = 0; mi < 4; ++mi) {
                    acc[mi][ni] = mfma16(ah[mi], bh, acc[mi][ni]);
                    acc[mi][ni] = mfma16(ah[mi], bl, acc[mi][ni]);
                    acc[mi][ni] = mfma16(al[mi], bh, acc[mi][ni]);
                }
            }
        }
    }
    #pragma unroll
    for (int mi = 0; mi < 4; ++mi)
        #pragma unroll
        for (int ni = 0; ni < 4; ++ni)
            #pragma unroll
            for (int r = 0; r < 4; ++r) {
                int row = rowA + wm + mi * 16 + g * 4 + r;
                int col = colB + wn + ni * 16 + l15;
                C[(size_t)row * N + col] = acc[mi][ni][r];
            }
}

// ---------------------------------------------------------------------------
// Convert K,V from fp32 qkv to split bf16. K: [bh][s][d] hi/lo. V: transposed
// AND slot-permuted [bh][d][slot], slot = (s&15)*4 + ((s>>4)&3) within each
// 64-block — the same permutation the flash kernel uses for P, so PV is exact.
// ---------------------------------------------------------------------------
__global__ __launch_bounds__(256)
void convert_kv(const float* __restrict__ qkv,
                bf16* __restrict__ Kh, bf16* __restrict__ Kl,
                bf16* __restrict__ Vth, bf16* __restrict__ Vtl) {
    const int st = blockIdx.x, h = blockIdx.y, b = blockIdx.z;
    const int bh = b * NH + h;
    __shared__ float VT[64][68];
    const int t = threadIdx.x;
    const int r = t >> 2, c16 = (t & 3) * 16;

    // K rows
    const size_t kbase = ((size_t)(b * SEQ + st * 64 + r) * 3 + 1) * DM + h * DK;
    #pragma unroll
    for (int u = 0; u < 2; ++u) {
        bf16x8 hh, ll;
        split8(&qkv[kbase + c16 + u * 8], 1.0f, hh, ll);
        size_t o = ((size_t)bh * SEQ + st * 64 + r) * DK + c16 + u * 8;
        *(bf16x8*)&Kh[o] = hh;
        *(bf16x8*)&Kl[o] = ll;
    }
    // V -> LDS fp32
    const size_t vbase = ((size_t)(b * SEQ + st * 64 + r) * 3 + 2) * DM + h * DK;
    #pragma unroll
    for (int u = 0; u < 4; ++u) {
        float4 v = *(const float4*)&qkv[vbase + c16 + u * 4];
        VT[r][c16 + u * 4 + 0] = v.x; VT[r][c16 + u * 4 + 1] = v.y;
        VT[r][c16 + u * 4 + 2] = v.z; VT[r][c16 + u * 4 + 3] = v.w;
    }
    __syncthreads();
    // transposed + permuted write: thread owns d=r, slots c16..c16+15
    bf16x8 vh0{}, vh1{}, vl0{}, vl1{};
    #pragma unroll
    for (int i = 0; i < 8; ++i) {
        int slot = c16 + i;
        float f = VT[(slot & 3) * 16 + (slot >> 2)][r];
        bf16 hh = (bf16)f;
        vh0[i] = hh; vl0[i] = (bf16)(f - (float)hh);
    }
    #pragma unroll
    for (int i = 0; i < 8; ++i) {
        int slot = c16 + 8 + i;
        float f = VT[(slot & 3) * 16 + (slot >> 2)][r];
        bf16 hh = (bf16)f;
        vh1[i] = hh; vl1[i] = (bf16)(f - (float)hh);
    }
    size_t vo = ((size_t)bh * DK + r) * SEQ + st * 64 + c16;
    *(bf16x8*)&Vth[vo] = vh0;     *(bf16x8*)&Vth[vo + 8] = vh1;
    *(bf16x8*)&Vtl[vo] = vl0;     *(bf16x8*)&Vtl[vo + 8] = vl1;
}

// ---------------------------------------------------------------------------
// MFMA flash attention. Block = 128 q-rows of one (b,h); 4 waves, each wave
// owns 32 q-rows. K/V tile = 64. 3-term split on QK^T and PV. Q in registers.
// ---------------------------------------------------------------------------
__global__ __launch_bounds__(256, 2)
void flash_mfma(const float* __restrict__ qkv,
                const bf16* __restrict__ Kh, const bf16* __restrict__ Kl,
                const bf16* __restrict__ Vth, const bf16* __restrict__ Vtl,
                float* __restrict__ att) {
    // XCD-bijective swizzle: nwg = 512 (divisible by 8), cpx = nwg/8.
    // (R2 bug: hardcoded 128 assumed nwg=1024 -> non-bijective -> OOB + holes.)
    const int nwg = (int)gridDim.x;
    const int cpx = nwg >> 3;
    const int bid = (int)blockIdx.x;
    const int wg = (bid & 7) * cpx + (bid >> 3);
    const int qt = wg & 31;
    const int bh = wg >> 5;
    const int h = bh & 7, b = bh >> 3;

    __shared__ bf16 KhS[64 * 64], KlS[64 * 64], VhS[64 * 64], VlS[64 * 64];
    __shared__ bf16 PhS[128 * 64], PlS[128 * 64];

    const int t = threadIdx.x, lane = t & 63, w = t >> 6;
    const int l15 = lane & 15, g = lane >> 4;
    const int q0 = qt * 128;
    const int wq = w * 32;

    // Q fragments held in registers (scaled by 1/8, split hi/lo)
    bf16x8 qh[2][2], ql[2][2];
    #pragma unroll
    for (int mi = 0; mi < 2; ++mi) {
        const int row = q0 + wq + mi * 16 + l15;
        const size_t base = ((size_t)(b * SEQ + row) * 3 + 0) * DM + h * DK + g * 8;
        #pragma unroll
        for (int kst = 0; kst < 2; ++kst)
            split8(&qkv[base + kst * 32], 0.125f, qh[mi][kst], ql[mi][kst]);
    }

    float m_run[2][4], l_run[2][4];
    f32x4 o[2][4] = {};
    #pragma unroll
    for (int mi = 0; mi < 2; ++mi)
        #pragma unroll
        for (int r = 0; r < 4; ++r) { m_run[mi][r] = -1e30f; l_run[mi][r] = 0.f; }

    const int sr = t >> 2, sc16 = (t & 3) * 16;

    for (int kt = 0; kt < SEQ / 64; ++kt) {
        __syncthreads();   // prev iter's PV done with V (and K from scores)
        const size_t ko = ((size_t)bh * SEQ + kt * 64 + sr) * DK + sc16;
        const size_t vo = ((size_t)bh * DK + sr) * SEQ + kt * 64 + sc16;
        #pragma unroll
        for (int u = 0; u < 2; ++u) {
            int off = swzE(sr, sc16 + u * 8);
            *(bf16x8*)&KhS[off] = *(const bf16x8*)&Kh[ko + u * 8];
            *(bf16x8*)&KlS[off] = *(const bf16x8*)&Kl[ko + u * 8];
            *(bf16x8*)&VhS[off] = *(const bf16x8*)&Vth[vo + u * 8];
            *(bf16x8*)&VlS[off] = *(const bf16x8*)&Vtl[vo + u * 8];
        }
        __syncthreads();

        // ---- scores: 3-term split MFMA ----
        f32x4 s[2][4] = {};
        #pragma unroll
        for (int kst = 0; kst < 2; ++kst) {
            #pragma unroll
            for (int ni = 0; ni < 4; ++ni) {
                int off = swzE(ni * 16 + l15, kst * 32 + g * 8);
                bf16x8 kh = *(const bf16x8*)&KhS[off];
                bf16x8 kl = *(const bf16x8*)&KlS[off];
                #pragma unroll
                for (int mi = 0; mi < 2; ++mi) {
                    s[mi][ni] = mfma16(qh[mi][kst], kh, s[mi][ni]);
                    s[mi][ni] = mfma16(qh[mi][kst], kl, s[mi][ni]);
                    s[mi][ni] = mfma16(ql[mi][kst], kh, s[mi][ni]);
                }
            }
        }

        // ---- online softmax; pack P (slot-permuted) as hi/lo b64 writes ----
        #pragma unroll
        for (int mi = 0; mi < 2; ++mi) {
            #pragma unroll
            for (int r = 0; r < 4; ++r) {
                float mx = fmaxf(fmaxf(s[mi][0][r], s[mi][1][r]),
                                 fmaxf(s[mi][2][r], s[mi][3][r]));
                #pragma unroll
                for (int off = 1; off < 16; off <<= 1)
                    mx = fmaxf(mx, __shfl_xor(mx, off));
                const float mnew  = fmaxf(m_run[mi][r], mx);
                const float alpha = __expf(m_run[mi][r] - mnew);
                float p0 = __expf(s[mi][0][r] - mnew);
                float p1 = __expf(s[mi][1][r] - mnew);
                float p2 = __expf(s[mi][2][r] - mnew);
                float p3 = __expf(s[mi][3][r] - mnew);
                float rs = (p0 + p1) + (p2 + p3);
                #pragma unroll
                for (int off = 1; off < 16; off <<= 1)
                    rs += __shfl_xor(rs, off);
                m_run[mi][r] = mnew;
                l_run[mi][r] = l_run[mi][r] * alpha + rs;
                #pragma unroll
                for (int ni = 0; ni < 4; ++ni) o[mi][ni][r] *= alpha;

                bf16 h0, l0, h1, l1, h2, l2, h3, l3;
                split2(p0, h0, l0); split2(p1, h1, l1);
                split2(p2, h2, l2); split2(p3, h3, l3);
                const int prow = wq + mi * 16 + g * 4 + r;
                const int e = swzE(prow, l15 * 4);
                *(bf16x4*)&PhS[e] = (bf16x4){h0, h1, h2, h3};
                *(bf16x4*)&PlS[e] = (bf16x4){l0, l1, l2, l3};
            }
        }
        // P is wave-private (same wave writes & reads its 32 rows): no barrier.

        // ---- O += P @ V (3-term split) ----
        #pragma unroll
        for (int kst = 0; kst < 2; ++kst) {
            bf16x8 ph[2], pl[2];
            #pragma unroll
            for (int mi = 0; mi < 2; ++mi) {
                int off = swzE(wq + mi * 16 + l15, kst * 32 + g * 8);
                ph[mi] = *(const bf16x8*)&PhS[off];
                pl[mi] = *(const bf16x8*)&PlS[off];
            }
            #pragma unroll
            for (int ni = 0; ni < 4; ++ni) {
                int off = swzE(ni * 16 + l15, kst * 32 + g * 8);
                bf16x8 vh = *(const bf16x8*)&VhS[off];
                bf16x8 vl = *(const bf16x8*)&VlS[off];
                #pragma unroll
                for (int mi = 0; mi < 2; ++mi) {
                    o[mi][ni] = mfma16(ph[mi], vh, o[mi][ni]);
                    o[mi][ni] = mfma16(ph[mi], vl, o[mi][ni]);
                    o[mi][ni] = mfma16(pl[mi], vh, o[mi][ni]);
                }
            }
        }
    }

    // ---- epilogue ----
    #pragma unroll
    for (int mi = 0; mi < 2; ++mi)
        #pragma unroll
        for (int r = 0; r < 4; ++r) {
            const float inv = 1.0f / l_run[mi][r];
            const int row = q0 + wq + mi * 16 + g * 4 + r;
            #pragma unroll
            for (int ni = 0; ni < 4; ++ni)
                att[(size_t)(b * SEQ + row) * DM + h * DK + ni * 16 + l15] =
                    o[mi][ni][r] * inv;
        }
}

// ---------------------------------------------------------------------------
extern "C" void kernel_launch(void* const* d_in, const int* in_sizes, int n_in,
                              void* d_out, int out_size, void* d_ws, size_t ws_size,
                              hipStream_t stream) {
    const float* x    = (const float*)d_in[0];
    const float* Wqkv = (const float*)d_in[1];
    const float* Wout = (const float*)d_in[2];
    float* out = (float*)d_out;

    char* ws = (char*)d_ws;
    float* qkv  = (float*)(ws);                          // 48 MB
    float* attn = (float*)(ws + (size_t)48 * 1048576);   // 16 MB
    bf16* Khp  = (bf16*)(ws + (size_t)64 * 1048576);     // 8 MB
    bf16* Klp  = (bf16*)(ws + (size_t)72 * 1048576);     // 8 MB
    bf16* Vthp = (bf16*)(ws + (size_t)80 * 1048576);     // 8 MB
    bf16* Vtlp = (bf16*)(ws + (size_t)88 * 1048576);     // 8 MB
    bf16* Wqh  = (bf16*)(ws + (size_t)96 * 1048576);     // 1.5 MB
    bf16* Wql  = (bf16*)(ws + (size_t)98 * 1048576);
    bf16* Woh  = (bf16*)(ws + (size_t)100 * 1048576);    // 0.5 MB
    bf16* Wol  = (bf16*)(ws + (size_t)101 * 1048576);

    const int M = NB * SEQ;   // 8192

    prep_w<<<dim3(DM / 64, (3 * DM) / 64), 256, 0, stream>>>(Wqkv, Wqh, Wql, DM, 3 * DM);
    prep_w<<<dim3(DM / 64, DM / 64), 256, 0, stream>>>(Wout, Woh, Wol, DM, DM);

    gemm_split<<<dim3((3 * DM) / 128, M / 128), 256, 0, stream>>>(
        x, Wqh, Wql, qkv, M, 3 * DM, DM);

    convert_kv<<<dim3(SEQ / 64, NH, NB), 256, 0, stream>>>(qkv, Khp, Klp, Vthp, Vtlp);

    flash_mfma<<<dim3((SEQ / 128) * NH * NB), 256, 0, stream>>>(
        qkv, Khp, Klp, Vthp, Vtlp, attn);

    gemm_split<<<dim3(DM / 128, M / 128), 256, 0, stream>>>(
        attn, Woh, Wol, out, M, DM, DM);
}